// Round 1
// baseline (1267.809 us; speedup 1.0000x reference)
//
#include <hip/hip_runtime.h>

#define N_SOURCE 100000
#define N_TARGET 50000
#define DIM 128
#define TFD 32
#define NE 640000

// Workspace layout
static constexpr size_t DEG_OFF = 0;                 // 100000 floats (only <50000 used)
static constexpr size_t ACC_OFF = 1 << 19;           // 524288 B
static constexpr size_t ACC_BYTES = (size_t)N_TARGET * DIM * 4;  // 25.6 MB

// K1: deg[r] += ew[e]
__global__ void deg_scatter(const int* __restrict__ row,
                            const float* __restrict__ ew,
                            float* __restrict__ deg) {
  int e = blockIdx.x * blockDim.x + threadIdx.x;
  if (e < NE) atomicAdd(&deg[row[e]], ew[e]);
}

// K2: acc[c, :] += rsqrt(deg[r]+1)*ew[e] * x[r, :]   (32 lanes per edge, float4 each)
__global__ void edge_scatter(const int* __restrict__ row,
                             const int* __restrict__ col,
                             const float* __restrict__ ew,
                             const float* __restrict__ deg,
                             const float* __restrict__ x,
                             float* __restrict__ acc) {
  int t = blockIdx.x * blockDim.x + threadIdx.x;
  int e = t >> 5;
  int lane = t & 31;
  if (e >= NE) return;
  int r = row[e];
  int c = col[e];
  float nrm = rsqrtf(deg[r] + 1.0f) * ew[e];
  float4 xv = ((const float4*)x)[(size_t)r * (DIM / 4) + lane];
  float* a = acc + (size_t)c * DIM + lane * 4;
  atomicAdd(a + 0, nrm * xv.x);
  atomicAdd(a + 1, nrm * xv.y);
  atomicAdd(a + 2, nrm * xv.z);
  atomicAdd(a + 3, nrm * xv.w);
}

__device__ __forceinline__ void fma4(float4& s, float a, const float4& w) {
  s.x = fmaf(a, w.x, s.x);
  s.y = fmaf(a, w.y, s.y);
  s.z = fmaf(a, w.z, s.z);
  s.w = fmaf(a, w.w, s.w);
}

// K3: out[i, 0:128] = relu(acc[i,:] @ W + bias), strided row pitch 160
__global__ __launch_bounds__(256) void gemm_bias_relu(
    const float* __restrict__ acc, const float* __restrict__ W,
    const float* __restrict__ bias, float* __restrict__ out) {
  __shared__ float4 Wl[DIM][DIM / 4];  // 64 KB: Wl[k][c4]
  __shared__ float4 Xl[32][DIM / 4];   // 16 KB: 32 rows of acc

  const int tid = threadIdx.x;
  for (int i = tid; i < DIM * DIM / 4; i += 256)
    ((float4*)Wl)[i] = ((const float4*)W)[i];

  const int lane = tid & 31;   // float4 column index (cols lane*4..lane*4+3)
  const int grp = tid >> 5;    // 0..7 -> row group of 4
  const float4 b4 = ((const float4*)bias)[lane];
  const int row0 = blockIdx.x * 32;

  for (int i = tid; i < 32 * (DIM / 4); i += 256) {
    int rr = i >> 5, kk = i & 31;
    int rg = row0 + rr;
    Xl[rr][kk] = (rg < N_TARGET)
                     ? ((const float4*)acc)[(size_t)rg * (DIM / 4) + kk]
                     : make_float4(0.f, 0.f, 0.f, 0.f);
  }
  __syncthreads();

  float4 s0 = {0, 0, 0, 0}, s1 = {0, 0, 0, 0}, s2 = {0, 0, 0, 0}, s3 = {0, 0, 0, 0};
  const int r0 = grp * 4;
#pragma unroll 8
  for (int k4 = 0; k4 < DIM / 4; ++k4) {
    float4 xa = Xl[r0 + 0][k4];
    float4 xb = Xl[r0 + 1][k4];
    float4 xc = Xl[r0 + 2][k4];
    float4 xd = Xl[r0 + 3][k4];
    float4 w0 = Wl[k4 * 4 + 0][lane];
    float4 w1 = Wl[k4 * 4 + 1][lane];
    float4 w2 = Wl[k4 * 4 + 2][lane];
    float4 w3 = Wl[k4 * 4 + 3][lane];
    fma4(s0, xa.x, w0); fma4(s0, xa.y, w1); fma4(s0, xa.z, w2); fma4(s0, xa.w, w3);
    fma4(s1, xb.x, w0); fma4(s1, xb.y, w1); fma4(s1, xb.z, w2); fma4(s1, xb.w, w3);
    fma4(s2, xc.x, w0); fma4(s2, xc.y, w1); fma4(s2, xc.z, w2); fma4(s2, xc.w, w3);
    fma4(s3, xd.x, w0); fma4(s3, xd.y, w1); fma4(s3, xd.z, w2); fma4(s3, xd.w, w3);
  }

  float4 rs[4] = {s0, s1, s2, s3};
#pragma unroll
  for (int j = 0; j < 4; ++j) {
    int i = row0 + r0 + j;
    if (i < N_TARGET) {
      float4 v = rs[j];
      v.x = fmaxf(v.x + b4.x, 0.f);
      v.y = fmaxf(v.y + b4.y, 0.f);
      v.z = fmaxf(v.z + b4.z, 0.f);
      v.w = fmaxf(v.w + b4.w, 0.f);
      ((float4*)(out + (size_t)i * (DIM + TFD)))[lane] = v;
    }
  }
}

// K4: out[i, 128:160] = |target_feat[i,:]|
__global__ void tf_abs(const float* __restrict__ tf, float* __restrict__ out) {
  int t = blockIdx.x * blockDim.x + threadIdx.x;
  if (t >= N_TARGET * (TFD / 4)) return;
  int i = t >> 3, j = t & 7;
  float4 v = ((const float4*)tf)[t];
  v.x = fabsf(v.x);
  v.y = fabsf(v.y);
  v.z = fabsf(v.z);
  v.w = fabsf(v.w);
  ((float4*)(out + (size_t)i * (DIM + TFD) + DIM))[j] = v;
}

extern "C" void kernel_launch(void* const* d_in, const int* in_sizes, int n_in,
                              void* d_out, int out_size, void* d_ws, size_t ws_size,
                              hipStream_t stream) {
  const float* x    = (const float*)d_in[0];
  const float* W    = (const float*)d_in[1];
  const float* bias = (const float*)d_in[2];
  const float* tf   = (const float*)d_in[3];
  const float* ew   = (const float*)d_in[4];
  const int*   eidx = (const int*)d_in[5];   // int64 request -> int32 under JAX default x64-off
  const int* row = eidx;
  const int* col = eidx + NE;
  float* out = (float*)d_out;
  float* deg = (float*)((char*)d_ws + DEG_OFF);
  float* acc = (float*)((char*)d_ws + ACC_OFF);

  // zero deg + acc (ws is poisoned 0xAA before every launch)
  hipMemsetAsync(d_ws, 0, ACC_OFF + ACC_BYTES, stream);

  deg_scatter<<<(NE + 255) / 256, 256, 0, stream>>>(row, ew, deg);
  edge_scatter<<<(NE * 32) / 256, 256, 0, stream>>>(row, col, ew, deg, x, acc);
  gemm_bias_relu<<<(N_TARGET + 31) / 32, 256, 0, stream>>>(acc, W, bias, out);
  tf_abs<<<(N_TARGET * (TFD / 4) + 255) / 256, 256, 0, stream>>>(tf, out);
}

// Round 5
// 405.113 us; speedup vs baseline: 3.1295x; 3.1295x over previous
//
#include <hip/hip_runtime.h>

#define N_SOURCE 100000
#define N_TARGET 50000
#define DIM 128
#define TFD 32
#define NE 640000

// ws layout (bytes)
static constexpr size_t DEG_OFF   = 0;          // 50000 f32 (200 KB)
static constexpr size_t CNT_OFF   = 262144;     // 50000 i32
static constexpr size_t OFFS_OFF  = 524288;     // 50001 i32
static constexpr size_t CURS_OFF  = 786432;     // 50000 i32
static constexpr size_t PAIRS_OFF = 1048576;    // 640000 int2 (5.12 MB)
static constexpr size_t ACC_OFF   = 8388608;    // 50000*128 f32 (25.6 MB)

// K1: deg[row] += ew  (float), cnt[col] += 1 (int)
__global__ void deg_cnt(const int* __restrict__ row, const int* __restrict__ col,
                        const float* __restrict__ ew,
                        float* __restrict__ deg, int* __restrict__ cnt) {
  int e = blockIdx.x * blockDim.x + threadIdx.x;
  if (e < NE) {
    atomicAdd(&deg[row[e]], ew[e]);
    atomicAdd(&cnt[col[e]], 1);
  }
}

// K2: exclusive scan of cnt -> offs[0..N], cursor copy. Single block, 1024 thr.
#define SCAN_T 1024
__global__ __launch_bounds__(SCAN_T) void scan_offsets(const int* __restrict__ cnt,
                                                       int* __restrict__ offs,
                                                       int* __restrict__ cursor) {
  __shared__ int s[SCAN_T];
  __shared__ int carry_s;
  const int tid = threadIdx.x;
  if (tid == 0) carry_s = 0;
  __syncthreads();
  for (int base = 0; base < N_TARGET; base += SCAN_T) {
    int i = base + tid;
    int v = (i < N_TARGET) ? cnt[i] : 0;
    s[tid] = v;
    __syncthreads();
#pragma unroll
    for (int d = 1; d < SCAN_T; d <<= 1) {
      int t = (tid >= d) ? s[tid - d] : 0;
      __syncthreads();
      s[tid] += t;
      __syncthreads();
    }
    int incl = s[tid];
    int carry = carry_s;  // read before anyone updates it (barrier below)
    if (i < N_TARGET) {
      int ex = carry + incl - v;
      offs[i] = ex;
      cursor[i] = ex;
    }
    __syncthreads();
    if (tid == SCAN_T - 1) carry_s = carry + incl;
    __syncthreads();
  }
  if (tid == 0) offs[N_TARGET] = carry_s;
}

// K3: CSR fill — pairs[pos] = (row, norm) sorted by col
__global__ void scatter_pairs(const int* __restrict__ row, const int* __restrict__ col,
                              const float* __restrict__ ew, const float* __restrict__ deg,
                              int* __restrict__ cursor, int2* __restrict__ pairs) {
  int e = blockIdx.x * blockDim.x + threadIdx.x;
  if (e >= NE) return;
  int c = col[e];
  int pos = atomicAdd(&cursor[c], 1);
  int r = row[e];
  float nrm = rsqrtf(deg[r] + 1.0f) * ew[e];
  pairs[pos] = make_int2(r, __float_as_int(nrm));
}

// K4: atomic-free segment sum. 32 lanes per target row (one float4 per lane).
__global__ __launch_bounds__(256) void gather_agg(const int* __restrict__ offs,
                                                  const int2* __restrict__ pairs,
                                                  const float* __restrict__ x,
                                                  float* __restrict__ acc) {
  int g = blockIdx.x * 8 + (threadIdx.x >> 5);
  int lane = threadIdx.x & 31;
  if (g >= N_TARGET) return;
  int beg = offs[g], end = offs[g + 1];
  const float4* __restrict__ x4 = (const float4*)x;
  float4 s = {0.f, 0.f, 0.f, 0.f};
  for (int j = beg; j < end; ++j) {
    int2 p = pairs[j];
    float nrm = __int_as_float(p.y);
    float4 xv = x4[(size_t)p.x * (DIM / 4) + lane];
    s.x = fmaf(nrm, xv.x, s.x);
    s.y = fmaf(nrm, xv.y, s.y);
    s.z = fmaf(nrm, xv.z, s.z);
    s.w = fmaf(nrm, xv.w, s.w);
  }
  ((float4*)acc)[(size_t)g * (DIM / 4) + lane] = s;
}

__device__ __forceinline__ void fma4(float4& s, float a, const float4& w) {
  s.x = fmaf(a, w.x, s.x);
  s.y = fmaf(a, w.y, s.y);
  s.z = fmaf(a, w.z, s.z);
  s.w = fmaf(a, w.w, s.w);
}

// K5: out[i, 0:128] = relu(acc[i,:] @ W + bias), row pitch 160
__global__ __launch_bounds__(256) void gemm_bias_relu(
    const float* __restrict__ acc, const float* __restrict__ W,
    const float* __restrict__ bias, float* __restrict__ out) {
  __shared__ float4 Wl[DIM][DIM / 4];  // 64 KB
  __shared__ float4 Xl[32][DIM / 4];   // 16 KB

  const int tid = threadIdx.x;
  for (int i = tid; i < DIM * DIM / 4; i += 256)
    ((float4*)Wl)[i] = ((const float4*)W)[i];

  const int lane = tid & 31;
  const int grp = tid >> 5;
  const float4 b4 = ((const float4*)bias)[lane];
  const int row0 = blockIdx.x * 32;

  for (int i = tid; i < 32 * (DIM / 4); i += 256) {
    int rr = i >> 5, kk = i & 31;
    int rg = row0 + rr;
    Xl[rr][kk] = (rg < N_TARGET)
                     ? ((const float4*)acc)[(size_t)rg * (DIM / 4) + kk]
                     : make_float4(0.f, 0.f, 0.f, 0.f);
  }
  __syncthreads();

  float4 s0 = {0, 0, 0, 0}, s1 = {0, 0, 0, 0}, s2 = {0, 0, 0, 0}, s3 = {0, 0, 0, 0};
  const int r0 = grp * 4;
#pragma unroll 8
  for (int k4 = 0; k4 < DIM / 4; ++k4) {
    float4 xa = Xl[r0 + 0][k4];
    float4 xb = Xl[r0 + 1][k4];
    float4 xc = Xl[r0 + 2][k4];
    float4 xd = Xl[r0 + 3][k4];
    float4 w0 = Wl[k4 * 4 + 0][lane];
    float4 w1 = Wl[k4 * 4 + 1][lane];
    float4 w2 = Wl[k4 * 4 + 2][lane];
    float4 w3 = Wl[k4 * 4 + 3][lane];
    fma4(s0, xa.x, w0); fma4(s0, xa.y, w1); fma4(s0, xa.z, w2); fma4(s0, xa.w, w3);
    fma4(s1, xb.x, w0); fma4(s1, xb.y, w1); fma4(s1, xb.z, w2); fma4(s1, xb.w, w3);
    fma4(s2, xc.x, w0); fma4(s2, xc.y, w1); fma4(s2, xc.z, w2); fma4(s2, xc.w, w3);
    fma4(s3, xd.x, w0); fma4(s3, xd.y, w1); fma4(s3, xd.z, w2); fma4(s3, xd.w, w3);
  }

  float4 rs[4] = {s0, s1, s2, s3};
#pragma unroll
  for (int j = 0; j < 4; ++j) {
    int i = row0 + r0 + j;
    if (i < N_TARGET) {
      float4 v = rs[j];
      v.x = fmaxf(v.x + b4.x, 0.f);
      v.y = fmaxf(v.y + b4.y, 0.f);
      v.z = fmaxf(v.z + b4.z, 0.f);
      v.w = fmaxf(v.w + b4.w, 0.f);
      ((float4*)(out + (size_t)i * (DIM + TFD)))[lane] = v;
    }
  }
}

// K6: out[i, 128:160] = |target_feat[i,:]|
__global__ void tf_abs(const float* __restrict__ tf, float* __restrict__ out) {
  int t = blockIdx.x * blockDim.x + threadIdx.x;
  if (t >= N_TARGET * (TFD / 4)) return;
  int i = t >> 3, j = t & 7;
  float4 v = ((const float4*)tf)[t];
  v.x = fabsf(v.x);
  v.y = fabsf(v.y);
  v.z = fabsf(v.z);
  v.w = fabsf(v.w);
  ((float4*)(out + (size_t)i * (DIM + TFD) + DIM))[j] = v;
}

extern "C" void kernel_launch(void* const* d_in, const int* in_sizes, int n_in,
                              void* d_out, int out_size, void* d_ws, size_t ws_size,
                              hipStream_t stream) {
  const float* x    = (const float*)d_in[0];
  const float* W    = (const float*)d_in[1];
  const float* bias = (const float*)d_in[2];
  const float* tf   = (const float*)d_in[3];
  const float* ew   = (const float*)d_in[4];
  const int*   eidx = (const int*)d_in[5];  // int64 request -> int32 (JAX x64 off)
  const int* row = eidx;
  const int* col = eidx + NE;
  float* out = (float*)d_out;

  float* deg    = (float*)((char*)d_ws + DEG_OFF);
  int*   cnt    = (int*)((char*)d_ws + CNT_OFF);
  int*   offs   = (int*)((char*)d_ws + OFFS_OFF);
  int*   cursor = (int*)((char*)d_ws + CURS_OFF);
  int2*  pairs  = (int2*)((char*)d_ws + PAIRS_OFF);
  float* acc    = (float*)((char*)d_ws + ACC_OFF);

  // zero deg + cnt only (everything else is fully overwritten each call)
  hipMemsetAsync(d_ws, 0, OFFS_OFF, stream);

  deg_cnt<<<(NE + 255) / 256, 256, 0, stream>>>(row, col, ew, deg, cnt);
  scan_offsets<<<1, SCAN_T, 0, stream>>>(cnt, offs, cursor);
  scatter_pairs<<<(NE + 255) / 256, 256, 0, stream>>>(row, col, ew, deg, cursor, pairs);
  gather_agg<<<N_TARGET / 8, 256, 0, stream>>>(offs, pairs, x, acc);
  gemm_bias_relu<<<(N_TARGET + 31) / 32, 256, 0, stream>>>(acc, W, bias, out);
  tf_abs<<<(N_TARGET * (TFD / 4) + 255) / 256, 256, 0, stream>>>(tf, out);
}